// Round 4
// baseline (54.175 us; speedup 1.0000x reference)
//
#include <hip/hip_runtime.h>

#define B_SIZE 4096
#define IN_F   8192
#define OUT_W  8194           // IN_F + 2 after slicing off the 2-pads
#define ROWS   16             // rows per block (8 even/odd pairs)
#define CHUNKS 8              // column chunks (grid.x), 1024 cols each

typedef float f32x4 __attribute__((ext_vector_type(4)));
typedef float f32x2 __attribute__((ext_vector_type(2)));

// ---------------------------------------------------------------------------
// Kernel 1: gather band coeffs, 4 threads per output column j in [0, IN_F):
//   d=0..2: coeff[j][d] = W[j+2, j+d]  (0 if j+d >= IN_F)
//   d=3   : coeff[j][3] = count(j+2) * bias[j+2]
// ---------------------------------------------------------------------------
__global__ __launch_bounds__(64) void coeff_kernel(
    const float* __restrict__ w, const float* __restrict__ bias,
    float* __restrict__ coeff) {
  const int gid = blockIdx.x * 64 + threadIdx.x;   // [0, 4*IN_F)
  const int j = gid >> 2;
  const int d = gid & 3;
  const size_t c = (size_t)j + 2;
  float v;
  if (d == 3) {
    const float cnt = 1.f + (j + 1 < IN_F ? 1.f : 0.f) + (j + 2 < IN_F ? 1.f : 0.f);
    v = cnt * bias[c];
  } else {
    v = (j + d < IN_F) ? w[c * IN_F + j + d] : 0.f;
  }
  coeff[4 * (size_t)j + d] = v;
}

// ---------------------------------------------------------------------------
// Kernel 2: streaming 3-tap band apply, row-parity aligned float4 stores.
//   out[b][c] = K[c]·x[b][c..c+2] + bias-term, coeffs in registers.
//   Even rows: thread stores cols j..j+3   -> (8194*r + j)*4 is 16B-aligned.
//   Odd rows:  thread stores cols j-2..j+1 -> (2 + j-2) ≡ 0 mod 4 -> aligned.
//   Rows processed in pairs for 4 independent loads (~48B/lane) in flight.
//   Global tail thread (j=8188) adds cols 8190..8193 on odd rows (one
//   aligned float4; coeff zeros make x[8192] unnecessary) and the two zero
//   cols 8192..8193 on even rows.
// ---------------------------------------------------------------------------
__global__ __launch_bounds__(256) void band_kernel(
    const float* __restrict__ x, const float4* __restrict__ coeff,
    float* __restrict__ out) {
  const int t = threadIdx.x;
  const int j = (blockIdx.x * 256 + t) * 4;          // [0, 8192) step 4

  // even-row window coeffs: cols j..j+3
  const float4 k0 = coeff[j];
  const float4 k1 = coeff[j + 1];
  const float4 k2 = coeff[j + 2];
  const float4 k3 = coeff[j + 3];
  // odd-row window adds cols j-2, j-1 (window overlap covers the rest)
  float4 km2 = make_float4(0.f, 0.f, 0.f, 0.f);
  float4 km1 = make_float4(0.f, 0.f, 0.f, 0.f);
  if (j > 0) { km2 = coeff[j - 2]; km1 = coeff[j - 1]; }

  const bool ghalo = (j + 4 < IN_F);                 // false only for j=8188
  const bool tail  = (j == IN_F - 4);                // global last thread
  float4 kt0 = make_float4(0.f, 0.f, 0.f, 0.f);
  float4 kt1 = make_float4(0.f, 0.f, 0.f, 0.f);
  if (tail) { kt0 = coeff[IN_F - 2]; kt1 = coeff[IN_F - 1]; }

  const int row0 = blockIdx.y * ROWS;

#pragma unroll 2
  for (int p = 0; p < ROWS / 2; ++p) {
    const size_t r0 = (size_t)(row0 + 2 * p);        // even row
    const size_t r1 = r0 + 1;                        // odd row
    const float* xr0 = x + r0 * (size_t)IN_F;
    const float* xr1 = x + r1 * (size_t)IN_F;

    const f32x4 xv0 = *reinterpret_cast<const f32x4*>(xr0 + j);
    const f32x2 xh0 = ghalo ? *reinterpret_cast<const f32x2*>(xr0 + j + 4)
                            : (f32x2){0.f, 0.f};
    const f32x2 xm  = (j > 0) ? *reinterpret_cast<const f32x2*>(xr1 + j - 2)
                              : (f32x2){0.f, 0.f};
    const f32x4 xv1 = *reinterpret_cast<const f32x4*>(xr1 + j);

    // even row: cols j..j+3 from x[j..j+5]
    const float o0 = fmaf(k0.x, xv0.x, fmaf(k0.y, xv0.y, fmaf(k0.z, xv0.z, k0.w)));
    const float o1 = fmaf(k1.x, xv0.y, fmaf(k1.y, xv0.z, fmaf(k1.z, xv0.w, k1.w)));
    const float o2 = fmaf(k2.x, xv0.z, fmaf(k2.y, xv0.w, fmaf(k2.z, xh0.x, k2.w)));
    const float o3 = fmaf(k3.x, xv0.w, fmaf(k3.y, xh0.x, fmaf(k3.z, xh0.y, k3.w)));
    __builtin_nontemporal_store((f32x4){o0, o1, o2, o3},
        reinterpret_cast<f32x4*>(out + r0 * (size_t)OUT_W + j));

    // odd row: cols j-2..j+1 from x[j-2..j+3]
    const float q0 = fmaf(km2.x, xm.x,  fmaf(km2.y, xm.y,  fmaf(km2.z, xv1.x, km2.w)));
    const float q1 = fmaf(km1.x, xm.y,  fmaf(km1.y, xv1.x, fmaf(km1.z, xv1.y, km1.w)));
    const float q2 = fmaf(k0.x,  xv1.x, fmaf(k0.y,  xv1.y, fmaf(k0.z,  xv1.z, k0.w)));
    const float q3 = fmaf(k1.x,  xv1.y, fmaf(k1.y,  xv1.z, fmaf(k1.z,  xv1.w, k1.w)));
    if (j > 0) {
      __builtin_nontemporal_store((f32x4){q0, q1, q2, q3},
          reinterpret_cast<f32x4*>(out + r1 * (size_t)OUT_W + j - 2));
    } else {
      __builtin_nontemporal_store((f32x2){q2, q3},
          reinterpret_cast<f32x2*>(out + r1 * (size_t)OUT_W));
    }

    if (tail) {
      // even row: cols 8192..8193 are exact zeros
      __builtin_nontemporal_store((f32x2){0.f, 0.f},
          reinterpret_cast<f32x2*>(out + r0 * (size_t)OUT_W + IN_F));
      // odd row: cols 8190..8193 (kt0.z = kt1.y = kt1.z = 0, no x[8192] needed)
      const float t0 = fmaf(kt0.x, xv1.z, fmaf(kt0.y, xv1.w, kt0.w));
      const float t1 = fmaf(kt1.x, xv1.w, kt1.w);
      __builtin_nontemporal_store((f32x4){t0, t1, 0.f, 0.f},
          reinterpret_cast<f32x4*>(out + r1 * (size_t)OUT_W + IN_F - 2));
    }
  }
}

extern "C" void kernel_launch(void* const* d_in, const int* in_sizes, int n_in,
                              void* d_out, int out_size, void* d_ws, size_t ws_size,
                              hipStream_t stream) {
  const float* x    = (const float*)d_in[0];   // [4096, 8192]
  const float* w    = (const float*)d_in[1];   // [8198, 8192]
  const float* bias = (const float*)d_in[2];   // [8198]
  float* out = (float*)d_out;                  // [4096, 8194]
  float* coeff = (float*)d_ws;                 // IN_F * 16 B = 128 KB scratch

  coeff_kernel<<<(4 * IN_F) / 64, 64, 0, stream>>>(w, bias, coeff);

  dim3 grid(CHUNKS, B_SIZE / ROWS);            // 8 x 256 = 2048 blocks
  band_kernel<<<grid, 256, 0, stream>>>(x, (const float4*)coeff, out);
}